// Round 5
// baseline (251.963 us; speedup 1.0000x reference)
//
#include <hip/hip_runtime.h>
#include <math.h>

// ---------------------------------------------------------------------------
// 2-layer GCN:  out = gcn(relu(gcn(x, W1, b1)), W2, b2)
// gcn(x,W,b)[c] = dinv[c] * ( y[c] + sum_{edges r->c} y[r] ) + b
//   where y[r] = dinv[r] * (x[r] @ W),  dinv = rsqrt(1 + indeg)
// CSR gather aggregation (feature-split passes, 16 edges in flight/wave);
// fp16 MFMA GEMM with fused fp32->fp16 conversion.
// ---------------------------------------------------------------------------

typedef _Float16 h8 __attribute__((ext_vector_type(8)));
typedef float    f32x4 __attribute__((ext_vector_type(4)));

__global__ void k_zero2(int* __restrict__ a, int* __restrict__ b, int n) {
    int i = blockIdx.x * blockDim.x + threadIdx.x;
    if (i < n) { a[i] = 0; b[i] = 0; }
}

__global__ void k_count(const int* __restrict__ col, int E, int* __restrict__ deg) {
    int i = blockIdx.x * blockDim.x + threadIdx.x;
    int s = gridDim.x * blockDim.x;
    for (int e = i; e < E; e += s) atomicAdd(&deg[col[e]], 1);
}

// --- 3-phase exclusive scan of deg[N] -> rowptr[N+1] (dinv fused in ph3) ---
__global__ __launch_bounds__(1024) void k_scan1(const int* __restrict__ deg, int N,
                                                int* __restrict__ incl, int* __restrict__ bsum) {
    __shared__ int sm[1024];
    int t = threadIdx.x;
    int i = blockIdx.x * 1024 + t;
    sm[t] = (i < N) ? deg[i] : 0;
    __syncthreads();
    for (int off = 1; off < 1024; off <<= 1) {
        int add = (t >= off) ? sm[t - off] : 0;
        __syncthreads();
        sm[t] += add;
        __syncthreads();
    }
    incl[i] = sm[t];
    if (t == 1023) bsum[blockIdx.x] = sm[t];
}

__global__ void k_scan2(const int* __restrict__ bsum, int* __restrict__ boff, int nb) {
    if (threadIdx.x == 0 && blockIdx.x == 0) {
        int run = 0;
        for (int b = 0; b < nb; b++) { boff[b] = run; run += bsum[b]; }
    }
}

__global__ void k_scan3(const int* __restrict__ incl, const int* __restrict__ boff,
                        const int* __restrict__ deg, int N,
                        int* __restrict__ rowptr, float* __restrict__ dinv) {
    int i = blockIdx.x * blockDim.x + threadIdx.x;
    if (i < N) {
        rowptr[i + 1] = incl[i] + boff[i >> 10];
        dinv[i] = rsqrtf((float)(1 + deg[i]));
    }
    if (i == 0) rowptr[0] = 0;
}

__global__ void k_fill(const int* __restrict__ row, const int* __restrict__ col, int E,
                       const int* __restrict__ rowptr, int* __restrict__ cursor,
                       int* __restrict__ srcidx) {
    int i = blockIdx.x * blockDim.x + threadIdx.x;
    int s = gridDim.x * blockDim.x;
    for (int e = i; e < E; e += s) {
        int c = col[e];
        int pos = rowptr[c] + atomicAdd(&cursor[c], 1);
        srcidx[pos] = row[e];
    }
}

// both weight transposes in one launch: wt[n][k] = (fp16) W[k][n]
__global__ void k_prep_w(const float* __restrict__ W1, const float* __restrict__ W2,
                         _Float16* __restrict__ wt1, _Float16* __restrict__ wt2,
                         int K, int n1, int n2) {
    int i = blockIdx.x * blockDim.x + threadIdx.x;
    int c1 = K * n1;
    if (i < c1) {
        int k = i / n1, n = i % n1;
        wt1[(long)n * K + k] = (_Float16)W1[i];
    } else if (i < c1 + K * n2) {
        int j = i - c1;
        int k = j / n2, n = j % n2;
        wt2[(long)n * K + k] = (_Float16)W2[j];
    }
}

// Y[m][n] = fp16( dinv[m] * sum_k X[m][k] * Wt[n][k] )
// 128x128 block tile, BK=32, 4 waves (2x2), each wave 64x64 via 4x4
// mfma_f32_16x16x32_f16 fragments. A32: read X as fp32, convert in staging.
template<bool A32>
__global__ __launch_bounds__(256) void k_gemm(
    const float* __restrict__ X32, const _Float16* __restrict__ X16,
    const _Float16* __restrict__ Wt, const float* __restrict__ dinv,
    _Float16* __restrict__ Y, int M, int K, int NC)
{
    __shared__ _Float16 As[128][40];  // row stride 80B (16B-aligned)
    __shared__ _Float16 Bs[128][40];

    const int bn = blockIdx.x * 128;
    const int bm = blockIdx.y * 128;
    const int tid = threadIdx.x;
    const int w = tid >> 6, l = tid & 63;
    const int wm = (w >> 1) * 64, wn = (w & 1) * 64;
    const int lr = l & 15, lg = l >> 4;

    f32x4 acc[4][4];
    #pragma unroll
    for (int i = 0; i < 4; i++)
        #pragma unroll
        for (int j = 0; j < 4; j++)
            acc[i][j] = (f32x4){0.f, 0.f, 0.f, 0.f};

    for (int k0 = 0; k0 < K; k0 += 32) {
        if (A32) {
            #pragma unroll
            for (int p = 0; p < 2; p++) {
                int rowi = p * 64 + (tid >> 2);
                int colA = (tid & 3) * 8;
                int gm = bm + rowi; if (gm >= M) gm = M - 1;
                float4 f0 = *reinterpret_cast<const float4*>(&X32[(long)gm * K + k0 + colA]);
                float4 f1 = *reinterpret_cast<const float4*>(&X32[(long)gm * K + k0 + colA + 4]);
                h8 hv;
                hv[0] = (_Float16)f0.x; hv[1] = (_Float16)f0.y;
                hv[2] = (_Float16)f0.z; hv[3] = (_Float16)f0.w;
                hv[4] = (_Float16)f1.x; hv[5] = (_Float16)f1.y;
                hv[6] = (_Float16)f1.z; hv[7] = (_Float16)f1.w;
                *reinterpret_cast<h8*>(&As[rowi][colA]) = hv;
            }
        } else {
            int rowi = tid >> 1;
            int colA = (tid & 1) * 16;
            int gm = bm + rowi; if (gm >= M) gm = M - 1;
            *reinterpret_cast<h8*>(&As[rowi][colA]) =
                *reinterpret_cast<const h8*>(&X16[(long)gm * K + k0 + colA]);
            *reinterpret_cast<h8*>(&As[rowi][colA + 8]) =
                *reinterpret_cast<const h8*>(&X16[(long)gm * K + k0 + colA + 8]);
        }
        {
            int n = tid >> 1;
            int colB = (tid & 1) * 16;
            *reinterpret_cast<h8*>(&Bs[n][colB]) =
                *reinterpret_cast<const h8*>(&Wt[(long)(bn + n) * K + k0 + colB]);
            *reinterpret_cast<h8*>(&Bs[n][colB + 8]) =
                *reinterpret_cast<const h8*>(&Wt[(long)(bn + n) * K + k0 + colB + 8]);
        }
        __syncthreads();

        h8 a[4], b[4];
        #pragma unroll
        for (int i = 0; i < 4; i++)
            a[i] = *reinterpret_cast<const h8*>(&As[wm + i * 16 + lr][lg * 8]);
        #pragma unroll
        for (int j = 0; j < 4; j++)
            b[j] = *reinterpret_cast<const h8*>(&Bs[wn + j * 16 + lr][lg * 8]);
        #pragma unroll
        for (int i = 0; i < 4; i++)
            #pragma unroll
            for (int j = 0; j < 4; j++)
                acc[i][j] = __builtin_amdgcn_mfma_f32_16x16x32_f16(
                    a[i], b[j], acc[i][j], 0, 0, 0);
        __syncthreads();
    }

    // C layout: row = (l>>4)*4 + reg, col = l&15
    #pragma unroll
    for (int i = 0; i < 4; i++) {
        #pragma unroll
        for (int r = 0; r < 4; r++) {
            int gm = bm + wm + i * 16 + lg * 4 + r;
            if (gm < M) {
                float s = dinv[gm];
                #pragma unroll
                for (int j = 0; j < 4; j++)
                    Y[(long)gm * NC + bn + wn + j * 16 + lr] =
                        (_Float16)(acc[i][j][r] * s);
            }
        }
    }
}

// out[node][fo : fo+LPR*8] = act( dinv*(Y[node]+sum_e Y[srcidx[e]]) + bias )
// One wave per node. LPR lanes cover the feature slice (16B/lane);
// G = 64/LPR edges per batch, 4-batch unroll -> 4G edges in flight.
// FT = full row stride (fp16 elems), fo = feature offset of this pass.
template<int LPR, bool F16OUT, bool RELU>
__global__ __launch_bounds__(256) void k_agg(
    const int* __restrict__ rowptr, const int* __restrict__ srcidx,
    const _Float16* __restrict__ Y, const float* __restrict__ dinv,
    const float* __restrict__ bias, int N, int FT, int fo,
    float* __restrict__ out32, _Float16* __restrict__ out16)
{
    const int G = 64 / LPR;   // edges per batch
    int node = blockIdx.x * 4 + (threadIdx.x >> 6);
    if (node >= N) return;
    int lane = threadIdx.x & 63;
    int sub = lane / LPR;
    int fl  = lane % LPR;
    const int fcol = fo + fl * 8;

    float acc[8];
    if (sub == 0) {  // self loop handled by subgroup 0
        h8 v = *reinterpret_cast<const h8*>(&Y[(long)node * FT + fcol]);
        #pragma unroll
        for (int j = 0; j < 8; j++) acc[j] = (float)v[j];
    } else {
        #pragma unroll
        for (int j = 0; j < 8; j++) acc[j] = 0.f;
    }

    int beg = rowptr[node], end = rowptr[node + 1];
    int cnt = end - beg;
    int i = beg + sub;
    int full = cnt / (4 * G);
    for (int t = 0; t < full; t++) {
        int r0 = srcidx[i];
        int r1 = srcidx[i + G];
        int r2 = srcidx[i + 2 * G];
        int r3 = srcidx[i + 3 * G];
        h8 v0 = *reinterpret_cast<const h8*>(&Y[(long)r0 * FT + fcol]);
        h8 v1 = *reinterpret_cast<const h8*>(&Y[(long)r1 * FT + fcol]);
        h8 v2 = *reinterpret_cast<const h8*>(&Y[(long)r2 * FT + fcol]);
        h8 v3 = *reinterpret_cast<const h8*>(&Y[(long)r3 * FT + fcol]);
        #pragma unroll
        for (int j = 0; j < 8; j++)
            acc[j] += ((float)v0[j] + (float)v1[j]) + ((float)v2[j] + (float)v3[j]);
        i += 4 * G;
    }
    for (; i < end; i += G) {
        int r = srcidx[i];
        h8 v = *reinterpret_cast<const h8*>(&Y[(long)r * FT + fcol]);
        #pragma unroll
        for (int j = 0; j < 8; j++) acc[j] += (float)v[j];
    }

    // merge sub-groups
    #pragma unroll
    for (int m = LPR; m < 64; m <<= 1)
        #pragma unroll
        for (int j = 0; j < 8; j++)
            acc[j] += __shfl_xor(acc[j], m, 64);

    float s = dinv[node];
    const float4* b4 = reinterpret_cast<const float4*>(&bias[fcol]);
    float4 blo = b4[0], bhi = b4[1];
    float r8[8];
    r8[0] = fmaf(s, acc[0], blo.x); r8[1] = fmaf(s, acc[1], blo.y);
    r8[2] = fmaf(s, acc[2], blo.z); r8[3] = fmaf(s, acc[3], blo.w);
    r8[4] = fmaf(s, acc[4], bhi.x); r8[5] = fmaf(s, acc[5], bhi.y);
    r8[6] = fmaf(s, acc[6], bhi.z); r8[7] = fmaf(s, acc[7], bhi.w);
    if (RELU) {
        #pragma unroll
        for (int j = 0; j < 8; j++) r8[j] = fmaxf(r8[j], 0.f);
    }

    long base = (long)node * FT + fcol;
    if (F16OUT) {
        if (sub == 0) {
            h8 o;
            #pragma unroll
            for (int j = 0; j < 8; j++) o[j] = (_Float16)r8[j];
            *reinterpret_cast<h8*>(&out16[base]) = o;
        }
    } else {
        if (sub == 0) {
            *reinterpret_cast<float4*>(&out32[base]) =
                make_float4(r8[0], r8[1], r8[2], r8[3]);
        } else if (sub == 1) {
            *reinterpret_cast<float4*>(&out32[base + 4]) =
                make_float4(r8[4], r8[5], r8[6], r8[7]);
        }
    }
}

extern "C" void kernel_launch(void* const* d_in, const int* in_sizes, int n_in,
                              void* d_out, int out_size, void* d_ws, size_t ws_size,
                              hipStream_t stream)
{
    const float* x   = (const float*)d_in[0];
    const int*   ei  = (const int*)d_in[1];
    const float* W1  = (const float*)d_in[2];
    const float* b1  = (const float*)d_in[3];
    const float* W2  = (const float*)d_in[4];
    const float* b2  = (const float*)d_in[5];

    const int nhid  = in_sizes[3];            // 256
    const int nfeat = in_sizes[5];            // 128
    const int N     = in_sizes[0] / nhid;     // 50000
    const int E     = in_sizes[1] / 2;        // 800000

    const int* row = ei;        // source
    const int* col = ei + E;    // target

    const int nb = (N + 1023) / 1024;

    size_t cur = 0;
    auto alloc = [&](size_t bytes) {
        void* p = (char*)d_ws + cur;
        cur += (bytes + 255) & ~(size_t)255;
        return p;
    };
    float*     dinv   = (float*)alloc((size_t)N * 4);
    int*       deg_i  = (int*)alloc((size_t)N * 4);
    int*       cursor = (int*)alloc((size_t)N * 4);
    int*       rowptr = (int*)alloc((size_t)(N + 1) * 4);
    int*       incl   = (int*)alloc((size_t)nb * 1024 * 4);
    int*       bsum   = (int*)alloc((size_t)nb * 4);
    int*       boff   = (int*)alloc((size_t)nb * 4);
    int*       srcidx = (int*)alloc((size_t)E * 4);
    _Float16*  wt1    = (_Float16*)alloc((size_t)nhid * nhid * 2);
    _Float16*  wt2    = (_Float16*)alloc((size_t)nhid * nfeat * 2);
    _Float16*  y16    = (_Float16*)alloc((size_t)N * nhid * 2);   // layer-1 y
    _Float16*  h16    = (_Float16*)alloc((size_t)N * nhid * 2);   // relu output
    _Float16*  y2     = (_Float16*)alloc((size_t)N * nfeat * 2);  // layer-2 y
    float*     out    = (float*)d_out;
    (void)ws_size; (void)n_in; (void)out_size;

    const int T = 256;

    // ---- CSR build + dinv + weight prep ----
    k_zero2<<<(N + T - 1) / T, T, 0, stream>>>(deg_i, cursor, N);
    k_count<<<1024, T, 0, stream>>>(col, E, deg_i);
    k_scan1<<<nb, 1024, 0, stream>>>(deg_i, N, incl, bsum);
    k_scan2<<<1, 64, 0, stream>>>(bsum, boff, nb);
    k_scan3<<<(N + T - 1) / T, T, 0, stream>>>(incl, boff, deg_i, N, rowptr, dinv);
    k_fill<<<1024, T, 0, stream>>>(row, col, E, rowptr, cursor, srcidx);
    k_prep_w<<<(nhid * (nhid + nfeat) + T - 1) / T, T, 0, stream>>>(
        W1, W2, wt1, wt2, nhid, nhid, nfeat);

    // ---- layer 1 ----
    {
        dim3 grid(nhid / 128, (N + 127) / 128);
        k_gemm<true><<<grid, T, 0, stream>>>(x, nullptr, wt1, dinv, y16, N, nhid, nhid);
    }
    // aggregation in two feature-half passes (12.8 MB working set each)
    k_agg<16, true, true><<<(N + 3) / 4, T, 0, stream>>>(
        rowptr, srcidx, y16, dinv, b1, N, nhid, 0, nullptr, h16);
    k_agg<16, true, true><<<(N + 3) / 4, T, 0, stream>>>(
        rowptr, srcidx, y16, dinv, b1, N, nhid, 128, nullptr, h16);

    // ---- layer 2 ----
    {
        dim3 grid(nfeat / 128, (N + 127) / 128);
        k_gemm<false><<<grid, T, 0, stream>>>(nullptr, h16, wt2, dinv, y2, N, nhid, nfeat);
    }
    k_agg<16, false, false><<<(N + 3) / 4, T, 0, stream>>>(
        rowptr, srcidx, y2, dinv, b2, N, nfeat, 0, out, nullptr);
}

// Round 6
// 237.195 us; speedup vs baseline: 1.0623x; 1.0623x over previous
//
#include <hip/hip_runtime.h>
#include <math.h>

// ---------------------------------------------------------------------------
// 2-layer GCN:  out = gcn(relu(gcn(x, W1, b1)), W2, b2)
// gcn(x,W,b)[c] = dinv[c] * ( y[c] + sum_{edges r->c} y[r] ) + b
//   where y[r] = dinv[r] * (x[r] @ W),  dinv = rsqrt(1 + indeg)
// CSR gather aggregation (feature-split passes); fp16 MFMA GEMM.
// CSR fill is fused into the GEMM1 launch (independent ops, shared machine).
// ---------------------------------------------------------------------------

typedef _Float16 h8 __attribute__((ext_vector_type(8)));
typedef float    f32x4 __attribute__((ext_vector_type(4)));

// init: zero deg/cursor (blocks [0,zb)) + both weight transposes (rest)
__global__ void k_init(int* __restrict__ deg, int* __restrict__ cursor, int N,
                       const float* __restrict__ W1, const float* __restrict__ W2,
                       _Float16* __restrict__ wt1, _Float16* __restrict__ wt2,
                       int K, int n1, int n2, int zb)
{
    if ((int)blockIdx.x < zb) {
        int i = blockIdx.x * blockDim.x + threadIdx.x;
        if (i < N) { deg[i] = 0; cursor[i] = 0; }
    } else {
        int i = (blockIdx.x - zb) * blockDim.x + threadIdx.x;
        int c1 = K * n1;
        if (i < c1) {
            int k = i / n1, n = i % n1;
            wt1[(long)n * K + k] = (_Float16)W1[i];
        } else if (i < c1 + K * n2) {
            int j = i - c1;
            int k = j / n2, n = j % n2;
            wt2[(long)n * K + k] = (_Float16)W2[j];
        }
    }
}

__global__ void k_count(const int* __restrict__ col, int E, int* __restrict__ deg) {
    int i = blockIdx.x * blockDim.x + threadIdx.x;
    int s = gridDim.x * blockDim.x;
    for (int e = i; e < E; e += s) atomicAdd(&deg[col[e]], 1);
}

// --- 3-phase exclusive scan of deg[N] -> rowptr[N+1] (dinv fused in ph3) ---
__global__ __launch_bounds__(1024) void k_scan1(const int* __restrict__ deg, int N,
                                                int* __restrict__ incl, int* __restrict__ bsum) {
    __shared__ int sm[1024];
    int t = threadIdx.x;
    int i = blockIdx.x * 1024 + t;
    sm[t] = (i < N) ? deg[i] : 0;
    __syncthreads();
    for (int off = 1; off < 1024; off <<= 1) {
        int add = (t >= off) ? sm[t - off] : 0;
        __syncthreads();
        sm[t] += add;
        __syncthreads();
    }
    incl[i] = sm[t];
    if (t == 1023) bsum[blockIdx.x] = sm[t];
}

__global__ void k_scan2(const int* __restrict__ bsum, int* __restrict__ boff, int nb) {
    if (threadIdx.x == 0 && blockIdx.x == 0) {
        int run = 0;
        for (int b = 0; b < nb; b++) { boff[b] = run; run += bsum[b]; }
    }
}

__global__ void k_scan3(const int* __restrict__ incl, const int* __restrict__ boff,
                        const int* __restrict__ deg, int N,
                        int* __restrict__ rowptr, float* __restrict__ dinv) {
    int i = blockIdx.x * blockDim.x + threadIdx.x;
    if (i < N) {
        rowptr[i + 1] = incl[i] + boff[i >> 10];
        dinv[i] = rsqrtf((float)(1 + deg[i]));
    }
    if (i == 0) rowptr[0] = 0;
}

// ---- shared GEMM body ----
// Y[m][n] = fp16( dinv[m] * sum_k X[m][k] * Wt[n][k] )
// 128x128 block tile, BK=32, 4 waves (2x2), each wave 64x64 via 4x4
// mfma_f32_16x16x32_f16 fragments. A32: read X as fp32, convert in staging.
template<bool A32>
__device__ __forceinline__ void gemm_body(
    const float* __restrict__ X32, const _Float16* __restrict__ X16,
    const _Float16* __restrict__ Wt, const float* __restrict__ dinv,
    _Float16* __restrict__ Y, int M, int K, int NC, int bx, int by)
{
    __shared__ _Float16 As[128][40];  // row stride 80B (16B-aligned)
    __shared__ _Float16 Bs[128][40];

    const int bn = bx * 128;
    const int bm = by * 128;
    const int tid = threadIdx.x;
    const int w = tid >> 6, l = tid & 63;
    const int wm = (w >> 1) * 64, wn = (w & 1) * 64;
    const int lr = l & 15, lg = l >> 4;

    f32x4 acc[4][4];
    #pragma unroll
    for (int i = 0; i < 4; i++)
        #pragma unroll
        for (int j = 0; j < 4; j++)
            acc[i][j] = (f32x4){0.f, 0.f, 0.f, 0.f};

    for (int k0 = 0; k0 < K; k0 += 32) {
        if (A32) {
            #pragma unroll
            for (int p = 0; p < 2; p++) {
                int rowi = p * 64 + (tid >> 2);
                int colA = (tid & 3) * 8;
                int gm = bm + rowi; if (gm >= M) gm = M - 1;
                float4 f0 = *reinterpret_cast<const float4*>(&X32[(long)gm * K + k0 + colA]);
                float4 f1 = *reinterpret_cast<const float4*>(&X32[(long)gm * K + k0 + colA + 4]);
                h8 hv;
                hv[0] = (_Float16)f0.x; hv[1] = (_Float16)f0.y;
                hv[2] = (_Float16)f0.z; hv[3] = (_Float16)f0.w;
                hv[4] = (_Float16)f1.x; hv[5] = (_Float16)f1.y;
                hv[6] = (_Float16)f1.z; hv[7] = (_Float16)f1.w;
                *reinterpret_cast<h8*>(&As[rowi][colA]) = hv;
            }
        } else {
            int rowi = tid >> 1;
            int colA = (tid & 1) * 16;
            int gm = bm + rowi; if (gm >= M) gm = M - 1;
            *reinterpret_cast<h8*>(&As[rowi][colA]) =
                *reinterpret_cast<const h8*>(&X16[(long)gm * K + k0 + colA]);
            *reinterpret_cast<h8*>(&As[rowi][colA + 8]) =
                *reinterpret_cast<const h8*>(&X16[(long)gm * K + k0 + colA + 8]);
        }
        {
            int n = tid >> 1;
            int colB = (tid & 1) * 16;
            *reinterpret_cast<h8*>(&Bs[n][colB]) =
                *reinterpret_cast<const h8*>(&Wt[(long)(bn + n) * K + k0 + colB]);
            *reinterpret_cast<h8*>(&Bs[n][colB + 8]) =
                *reinterpret_cast<const h8*>(&Wt[(long)(bn + n) * K + k0 + colB + 8]);
        }
        __syncthreads();

        h8 a[4], b[4];
        #pragma unroll
        for (int i = 0; i < 4; i++)
            a[i] = *reinterpret_cast<const h8*>(&As[wm + i * 16 + lr][lg * 8]);
        #pragma unroll
        for (int j = 0; j < 4; j++)
            b[j] = *reinterpret_cast<const h8*>(&Bs[wn + j * 16 + lr][lg * 8]);
        #pragma unroll
        for (int i = 0; i < 4; i++)
            #pragma unroll
            for (int j = 0; j < 4; j++)
                acc[i][j] = __builtin_amdgcn_mfma_f32_16x16x32_f16(
                    a[i], b[j], acc[i][j], 0, 0, 0);
        __syncthreads();
    }

    // C layout: row = (l>>4)*4 + reg, col = l&15
    #pragma unroll
    for (int i = 0; i < 4; i++) {
        #pragma unroll
        for (int r = 0; r < 4; r++) {
            int gm = bm + wm + i * 16 + lg * 4 + r;
            if (gm < M) {
                float s = dinv[gm];
                #pragma unroll
                for (int j = 0; j < 4; j++)
                    Y[(long)gm * NC + bn + wn + j * 16 + lr] =
                        (_Float16)(acc[i][j][r] * s);
            }
        }
    }
}

// Fused: blocks [0,nfb) do the CSR srcidx fill; the rest do GEMM1 tiles.
// Both only depend on scan3 outputs (rowptr, dinv) -> can share one launch.
__global__ __launch_bounds__(256) void k_fill_gemm(
    const int* __restrict__ row, const int* __restrict__ col, int E,
    const int* __restrict__ rowptr, int* __restrict__ cursor, int* __restrict__ srcidx,
    int nfb,
    const float* __restrict__ X32, const _Float16* __restrict__ Wt,
    const float* __restrict__ dinv, _Float16* __restrict__ Y,
    int M, int K, int NC, int gx)
{
    if ((int)blockIdx.x < nfb) {
        int i = blockIdx.x * blockDim.x + threadIdx.x;
        int s = nfb * blockDim.x;
        for (int e = i; e < E; e += s) {
            int c = col[e];
            int pos = rowptr[c] + atomicAdd(&cursor[c], 1);
            srcidx[pos] = row[e];
        }
        return;
    }
    int gb = blockIdx.x - nfb;
    gemm_body<true>(X32, nullptr, Wt, dinv, Y, M, K, NC, gb % gx, gb / gx);
}

__global__ __launch_bounds__(256) void k_gemm16(
    const _Float16* __restrict__ X16, const _Float16* __restrict__ Wt,
    const float* __restrict__ dinv, _Float16* __restrict__ Y,
    int M, int K, int NC)
{
    gemm_body<false>(nullptr, X16, Wt, dinv, Y, M, K, NC, blockIdx.x, blockIdx.y);
}

// out[node][fo : fo+128] = act( dinv*(Y[node]+sum_e Y[srcidx[e]]) + bias )
// One wave per node. LPR lanes cover the feature slice (16B/lane);
// G = 64/LPR edges per batch, 4-batch unroll -> 4G edges in flight.
template<int LPR, bool F16OUT, bool RELU>
__global__ __launch_bounds__(256) void k_agg(
    const int* __restrict__ rowptr, const int* __restrict__ srcidx,
    const _Float16* __restrict__ Y, const float* __restrict__ dinv,
    const float* __restrict__ bias, int N, int FT, int fo,
    float* __restrict__ out32, _Float16* __restrict__ out16)
{
    const int G = 64 / LPR;   // edges per batch
    int node = blockIdx.x * 4 + (threadIdx.x >> 6);
    if (node >= N) return;
    int lane = threadIdx.x & 63;
    int sub = lane / LPR;
    int fl  = lane % LPR;
    const int fcol = fo + fl * 8;

    float acc[8];
    if (sub == 0) {  // self loop handled by subgroup 0
        h8 v = *reinterpret_cast<const h8*>(&Y[(long)node * FT + fcol]);
        #pragma unroll
        for (int j = 0; j < 8; j++) acc[j] = (float)v[j];
    } else {
        #pragma unroll
        for (int j = 0; j < 8; j++) acc[j] = 0.f;
    }

    int beg = rowptr[node], end = rowptr[node + 1];
    int cnt = end - beg;
    int i = beg + sub;
    int full = cnt / (4 * G);
    for (int t = 0; t < full; t++) {
        int r0 = srcidx[i];
        int r1 = srcidx[i + G];
        int r2 = srcidx[i + 2 * G];
        int r3 = srcidx[i + 3 * G];
        h8 v0 = *reinterpret_cast<const h8*>(&Y[(long)r0 * FT + fcol]);
        h8 v1 = *reinterpret_cast<const h8*>(&Y[(long)r1 * FT + fcol]);
        h8 v2 = *reinterpret_cast<const h8*>(&Y[(long)r2 * FT + fcol]);
        h8 v3 = *reinterpret_cast<const h8*>(&Y[(long)r3 * FT + fcol]);
        #pragma unroll
        for (int j = 0; j < 8; j++)
            acc[j] += ((float)v0[j] + (float)v1[j]) + ((float)v2[j] + (float)v3[j]);
        i += 4 * G;
    }
    for (; i < end; i += G) {
        int r = srcidx[i];
        h8 v = *reinterpret_cast<const h8*>(&Y[(long)r * FT + fcol]);
        #pragma unroll
        for (int j = 0; j < 8; j++) acc[j] += (float)v[j];
    }

    // merge sub-groups
    #pragma unroll
    for (int m = LPR; m < 64; m <<= 1)
        #pragma unroll
        for (int j = 0; j < 8; j++)
            acc[j] += __shfl_xor(acc[j], m, 64);

    float s = dinv[node];
    const float4* b4 = reinterpret_cast<const float4*>(&bias[fcol]);
    float4 blo = b4[0], bhi = b4[1];
    float r8[8];
    r8[0] = fmaf(s, acc[0], blo.x); r8[1] = fmaf(s, acc[1], blo.y);
    r8[2] = fmaf(s, acc[2], blo.z); r8[3] = fmaf(s, acc[3], blo.w);
    r8[4] = fmaf(s, acc[4], bhi.x); r8[5] = fmaf(s, acc[5], bhi.y);
    r8[6] = fmaf(s, acc[6], bhi.z); r8[7] = fmaf(s, acc[7], bhi.w);
    if (RELU) {
        #pragma unroll
        for (int j = 0; j < 8; j++) r8[j] = fmaxf(r8[j], 0.f);
    }

    long base = (long)node * FT + fcol;
    if (F16OUT) {
        if (sub == 0) {
            h8 o;
            #pragma unroll
            for (int j = 0; j < 8; j++) o[j] = (_Float16)r8[j];
            *reinterpret_cast<h8*>(&out16[base]) = o;
        }
    } else {
        if (sub == 0) {
            *reinterpret_cast<float4*>(&out32[base]) =
                make_float4(r8[0], r8[1], r8[2], r8[3]);
        } else if (sub == 1) {
            *reinterpret_cast<float4*>(&out32[base + 4]) =
                make_float4(r8[4], r8[5], r8[6], r8[7]);
        }
    }
}

extern "C" void kernel_launch(void* const* d_in, const int* in_sizes, int n_in,
                              void* d_out, int out_size, void* d_ws, size_t ws_size,
                              hipStream_t stream)
{
    const float* x   = (const float*)d_in[0];
    const int*   ei  = (const int*)d_in[1];
    const float* W1  = (const float*)d_in[2];
    const float* b1  = (const float*)d_in[3];
    const float* W2  = (const float*)d_in[4];
    const float* b2  = (const float*)d_in[5];

    const int nhid  = in_sizes[3];            // 256
    const int nfeat = in_sizes[5];            // 128
    const int N     = in_sizes[0] / nhid;     // 50000
    const int E     = in_sizes[1] / 2;        // 800000

    const int* row = ei;        // source
    const int* col = ei + E;    // target

    const int nb = (N + 1023) / 1024;

    size_t cur = 0;
    auto alloc = [&](size_t bytes) {
        void* p = (char*)d_ws + cur;
        cur += (bytes + 255) & ~(size_t)255;
        return p;
    };
    float*     dinv   = (float*)alloc((size_t)N * 4);
    int*       deg_i  = (int*)alloc((size_t)N * 4);
    int*       cursor = (int*)alloc((size_t)N * 4);
    int*       rowptr = (int*)alloc((size_t)(N + 1) * 4);
    int*       incl   = (int*)alloc((size_t)nb * 1024 * 4);
    int*       bsum   = (int*)alloc((size_t)nb * 4);
    int*       boff   = (int*)alloc((size_t)nb * 4);
    int*       srcidx = (int*)alloc((size_t)E * 4);
    _Float16*  wt1    = (_Float16*)alloc((size_t)nhid * nhid * 2);
    _Float16*  wt2    = (_Float16*)alloc((size_t)nhid * nfeat * 2);
    _Float16*  y16    = (_Float16*)alloc((size_t)N * nhid * 2);   // layer-1 y
    _Float16*  h16    = (_Float16*)alloc((size_t)N * nhid * 2);   // relu output
    _Float16*  y2     = (_Float16*)alloc((size_t)N * nfeat * 2);  // layer-2 y
    float*     out    = (float*)d_out;
    (void)ws_size; (void)n_in; (void)out_size;

    const int T = 256;

    // ---- init (zero histograms + weight transposes, one launch) ----
    {
        int zb = (N + T - 1) / T;
        int pb = (nhid * (nhid + nfeat) + T - 1) / T;
        k_init<<<zb + pb, T, 0, stream>>>(deg_i, cursor, N, W1, W2, wt1, wt2,
                                          nhid, nhid, nfeat, zb);
    }
    // ---- CSR build ----
    k_count<<<1024, T, 0, stream>>>(col, E, deg_i);
    k_scan1<<<nb, 1024, 0, stream>>>(deg_i, N, incl, bsum);
    k_scan2<<<1, 64, 0, stream>>>(bsum, boff, nb);
    k_scan3<<<(N + T - 1) / T, T, 0, stream>>>(incl, boff, deg_i, N, rowptr, dinv);

    // ---- fused: CSR fill (1024 blocks) || GEMM1 (2 x 391 tiles) ----
    {
        const int nfb = 1024;
        int gx = nhid / 128;
        int gy = (N + 127) / 128;
        k_fill_gemm<<<nfb + gx * gy, T, 0, stream>>>(
            row, col, E, rowptr, cursor, srcidx, nfb,
            x, wt1, dinv, y16, N, nhid, nhid, gx);
    }

    // ---- layer 1 aggregation: two feature-half passes ----
    k_agg<16, true, true><<<(N + 3) / 4, T, 0, stream>>>(
        rowptr, srcidx, y16, dinv, b1, N, nhid, 0, nullptr, h16);
    k_agg<16, true, true><<<(N + 3) / 4, T, 0, stream>>>(
        rowptr, srcidx, y16, dinv, b1, N, nhid, 128, nullptr, h16);

    // ---- layer 2 ----
    {
        dim3 grid(nfeat / 128, (N + 127) / 128);
        k_gemm16<<<grid, T, 0, stream>>>(h16, wt2, dinv, y2, N, nhid, nfeat);
    }
    k_agg<16, false, false><<<(N + 3) / 4, T, 0, stream>>>(
        rowptr, srcidx, y2, dinv, b2, N, nfeat, 0, out, nullptr);
}